// Round 1
// baseline (702.857 us; speedup 1.0000x reference)
//
#include <hip/hip_runtime.h>
#include <cstddef>
#include <cstdint>

// Problem constants (from reference)
static constexpr int IN_C  = 128;
static constexpr int HID_C = 128;
static constexpr int OUT_C = 64;
static constexpr float BN_EPS = 1e-5f;

// ---------------------------------------------------------------------------
// Degree / histogram: deg_src (for norm) and cnt_dst (for CSR build)
__global__ void edge_deg_k(const int* __restrict__ src, const int* __restrict__ dst,
                           int* __restrict__ deg_src, int* __restrict__ cnt_dst, int e_cnt) {
    int e = blockIdx.x * blockDim.x + threadIdx.x;
    if (e < e_cnt) {
        atomicAdd(&deg_src[src[e]], 1);
        atomicAdd(&cnt_dst[dst[e]], 1);
    }
}

__global__ void dinv_k(const int* __restrict__ deg, float* __restrict__ dinv, int n) {
    int i = blockIdx.x * blockDim.x + threadIdx.x;
    if (i < n) {
        int d = deg[i];
        dinv[i] = (d > 0) ? rsqrtf((float)d) : 0.f;
    }
}

// Single-block exclusive scan of cnt -> row_ptr (n up to ~50k, 1024 threads)
__global__ void scan_k(const int* __restrict__ cnt, int* __restrict__ row_ptr, int n) {
    __shared__ int sm[1024];
    int running = 0;
    for (int base = 0; base < n; base += 1024) {
        int i = base + threadIdx.x;
        int v = (i < n) ? cnt[i] : 0;
        sm[threadIdx.x] = v;
        __syncthreads();
        for (int off = 1; off < 1024; off <<= 1) {
            int t = (threadIdx.x >= off) ? sm[threadIdx.x - off] : 0;
            __syncthreads();
            sm[threadIdx.x] += t;
            __syncthreads();
        }
        int incl = sm[threadIdx.x];
        if (i < n) row_ptr[i + 1] = running + incl;
        if (base == 0 && threadIdx.x == 0) row_ptr[0] = 0;
        running += sm[1023];
        __syncthreads();
    }
}

// Fill CSR: col = src, val = -dinv[src]*dinv[dst], bucketed by dst
__global__ void fill_csr_k(const int* __restrict__ src, const int* __restrict__ dst,
                           const float* __restrict__ dinv, const int* __restrict__ row_ptr,
                           int* __restrict__ cursor, int* __restrict__ col,
                           float* __restrict__ val, int e_cnt) {
    int e = blockIdx.x * blockDim.x + threadIdx.x;
    if (e < e_cnt) {
        int s = src[e], t = dst[e];
        float nv = -dinv[s] * dinv[t];
        int pos = row_ptr[t] + atomicAdd(&cursor[t], 1);
        col[pos] = s;
        val[pos] = nv;
    }
}

// Propagate: out[i,:] = sum_{e in row i} val[e] * in[col[e],:]   (F=128)
// One wave per node; each lane owns a float2 of the feature row.
__global__ __launch_bounds__(256) void propagate_k(
    const float* __restrict__ in, float* __restrict__ out,
    const int* __restrict__ row_ptr, const int* __restrict__ col,
    const float* __restrict__ val, int n) {
    int wid = (blockIdx.x * 256 + threadIdx.x) >> 6;
    if (wid >= n) return;
    int lane = threadIdx.x & 63;
    int s = row_ptr[wid], e = row_ptr[wid + 1];
    float2 acc = make_float2(0.f, 0.f);
    for (int i = s; i < e; ++i) {
        int c = col[i];
        float w = val[i];
        float2 v = *(const float2*)(in + (size_t)c * 128 + lane * 2);
        acc.x += w * v.x;
        acc.y += w * v.y;
    }
    *(float2*)(out + (size_t)wid * 128 + lane * 2) = acc;
}

// Dual GEMM: C[n,CO] = A0[n,128]@W0[128,CO] + A1[n,128]@W1[128,CO] + bias
// BM=64, BK=16, 256 threads. Each thread: RPT rows x 4 cols.
template <int CO>
__global__ __launch_bounds__(256) void gemm_dual_k(
    const float* __restrict__ A0, const float* __restrict__ A1,
    const float* __restrict__ W0, const float* __restrict__ W1,
    const float* __restrict__ bias, float* __restrict__ C, int n) {
    constexpr int BM = 64, BK = 16;
    constexpr int COLT = CO / 4;
    constexpr int ROWT = 256 / COLT;
    constexpr int RPT = BM / ROWT;
    __shared__ float sA0[BK][BM];
    __shared__ float sA1[BK][BM];
    __shared__ float sW0[BK][CO];
    __shared__ float sW1[BK][CO];

    int block_row = blockIdx.x * BM;
    int tid = threadIdx.x;
    int tc = tid % COLT;
    int tr = tid / COLT;
    int c0 = tc * 4;
    int r0 = tr * RPT;

    float acc[RPT][4];
#pragma unroll
    for (int r = 0; r < RPT; ++r)
#pragma unroll
        for (int j = 0; j < 4; ++j) acc[r][j] = 0.f;

    for (int k0 = 0; k0 < 128; k0 += BK) {
        // A tiles: 64 rows x 16 k, 256 threads x float4 (transposed store)
        {
            int row = tid >> 2;
            int kk = (tid & 3) * 4;
            int grow = block_row + row;
            float4 a0 = make_float4(0.f, 0.f, 0.f, 0.f);
            float4 a1 = a0;
            if (grow < n) {
                a0 = *(const float4*)(A0 + (size_t)grow * 128 + k0 + kk);
                a1 = *(const float4*)(A1 + (size_t)grow * 128 + k0 + kk);
            }
            sA0[kk + 0][row] = a0.x; sA0[kk + 1][row] = a0.y;
            sA0[kk + 2][row] = a0.z; sA0[kk + 3][row] = a0.w;
            sA1[kk + 0][row] = a1.x; sA1[kk + 1][row] = a1.y;
            sA1[kk + 2][row] = a1.z; sA1[kk + 3][row] = a1.w;
        }
        // W tiles: 16 x CO
        for (int i = tid; i < BK * CO / 4; i += 256) {
            int kk = i / (CO / 4);
            int cc = (i % (CO / 4)) * 4;
            *(float4*)&sW0[kk][cc] = *(const float4*)(W0 + (size_t)(k0 + kk) * CO + cc);
            *(float4*)&sW1[kk][cc] = *(const float4*)(W1 + (size_t)(k0 + kk) * CO + cc);
        }
        __syncthreads();
#pragma unroll
        for (int kk = 0; kk < BK; ++kk) {
            float4 w0 = *(const float4*)&sW0[kk][c0];
            float4 w1 = *(const float4*)&sW1[kk][c0];
#pragma unroll
            for (int r = 0; r < RPT; ++r) {
                float a0 = sA0[kk][r0 + r];
                float a1 = sA1[kk][r0 + r];
                acc[r][0] += a0 * w0.x + a1 * w1.x;
                acc[r][1] += a0 * w0.y + a1 * w1.y;
                acc[r][2] += a0 * w0.z + a1 * w1.z;
                acc[r][3] += a0 * w0.w + a1 * w1.w;
            }
        }
        __syncthreads();
    }

    float4 b4 = *(const float4*)(bias + c0);
#pragma unroll
    for (int r = 0; r < RPT; ++r) {
        int grow = block_row + r0 + r;
        if (grow < n) {
            float4 o;
            o.x = acc[r][0] + b4.x;
            o.y = acc[r][1] + b4.y;
            o.z = acc[r][2] + b4.z;
            o.w = acc[r][3] + b4.w;
            *(float4*)(C + (size_t)grow * CO + c0) = o;
        }
    }
}

// BN column stats: partial sums + atomics. 128 threads/block, one col/thread.
__global__ void bn_stats_k(const float* __restrict__ h, float* __restrict__ stats, int n) {
    int c = threadIdx.x;  // 0..127
    float s = 0.f, ss = 0.f;
    for (int r = blockIdx.x; r < n; r += gridDim.x) {
        float v = h[(size_t)r * 128 + c];
        s += v;
        ss += v * v;
    }
    atomicAdd(&stats[c], s);
    atomicAdd(&stats[128 + c], ss);
}

__global__ void bn_finalize_k(const float* __restrict__ stats, const float* __restrict__ gamma,
                              const float* __restrict__ beta, float* __restrict__ p, float inv_n) {
    int c = threadIdx.x;  // 128 threads
    float mean = stats[c] * inv_n;
    float var = stats[128 + c] * inv_n - mean * mean;
    float sc = gamma[c] * rsqrtf(var + BN_EPS);
    p[c] = sc;
    p[128 + c] = beta[c] - mean * sc;
}

__global__ void bn_apply_relu_k(float* __restrict__ h, const float* __restrict__ p, int n) {
    int i = blockIdx.x * blockDim.x + threadIdx.x;  // per float4, n*32 total
    if (i >= n * 32) return;
    int c4 = (i & 31) * 4;
    float4 sc = *(const float4*)(p + c4);
    float4 sh = *(const float4*)(p + 128 + c4);
    float4 v = ((float4*)h)[i];
    v.x = fmaxf(v.x * sc.x + sh.x, 0.f);
    v.y = fmaxf(v.y * sc.y + sh.y, 0.f);
    v.z = fmaxf(v.z * sc.z + sh.z, 0.f);
    v.w = fmaxf(v.w * sc.w + sh.w, 0.f);
    ((float4*)h)[i] = v;
}

// ---------------------------------------------------------------------------
extern "C" void kernel_launch(void* const* d_in, const int* in_sizes, int n_in,
                              void* d_out, int out_size, void* d_ws, size_t ws_size,
                              hipStream_t stream) {
    const float* x = (const float*)d_in[0];
    const int* edge_index = (const int*)d_in[1];
    const float* W1_0 = (const float*)d_in[2];
    const float* W1_1 = (const float*)d_in[3];
    const float* b1 = (const float*)d_in[4];
    const float* gamma = (const float*)d_in[5];
    const float* beta = (const float*)d_in[6];
    const float* Wmu_0 = (const float*)d_in[7];
    const float* Wmu_1 = (const float*)d_in[8];
    const float* b_mu = (const float*)d_in[9];
    const float* Wls_0 = (const float*)d_in[10];
    const float* Wls_1 = (const float*)d_in[11];
    const float* b_ls = (const float*)d_in[12];

    const int N = in_sizes[0] / IN_C;   // 50000
    const int E = in_sizes[1] / 2;      // 800000
    const int* src = edge_index;
    const int* dst = edge_index + E;

    // Workspace layout (16B-aligned chunks)
    char* w = (char*)d_ws;
    auto alloc = [&](size_t bytes) {
        char* p = w;
        w += (bytes + 15) & ~(size_t)15;
        return p;
    };
    int* deg_cnt = (int*)alloc((size_t)N * 4);       // zeroed
    int* cnt_dst = (int*)alloc((size_t)N * 4);       // zeroed
    int* cursor = (int*)alloc((size_t)N * 4);        // zeroed
    float* stats = (float*)alloc(256 * 4);           // zeroed
    size_t zero_bytes = (size_t)((char*)w - (char*)deg_cnt);
    int* row_ptr = (int*)alloc((size_t)(N + 1) * 4);
    float* dinv = (float*)alloc((size_t)N * 4);
    int* col = (int*)alloc((size_t)E * 4);
    float* val = (float*)alloc((size_t)E * 4);
    float* xp = (float*)alloc((size_t)N * IN_C * 4);
    float* h = (float*)alloc((size_t)N * HID_C * 4);
    float* hp = (float*)alloc((size_t)N * HID_C * 4);

    float* out_mu = (float*)d_out;
    float* out_ls = out_mu + (size_t)N * OUT_C;

    hipMemsetAsync(deg_cnt, 0, zero_bytes, stream);

    int eb = (E + 255) / 256;
    int nb = (N + 255) / 256;
    edge_deg_k<<<eb, 256, 0, stream>>>(src, dst, deg_cnt, cnt_dst, E);
    dinv_k<<<nb, 256, 0, stream>>>(deg_cnt, dinv, N);
    scan_k<<<1, 1024, 0, stream>>>(cnt_dst, row_ptr, N);
    fill_csr_k<<<eb, 256, 0, stream>>>(src, dst, dinv, row_ptr, cursor, col, val, E);

    int pb = (N + 3) / 4;  // 4 waves/block, one node/wave
    propagate_k<<<pb, 256, 0, stream>>>(x, xp, row_ptr, col, val, N);

    int gb = (N + 63) / 64;
    gemm_dual_k<128><<<gb, 256, 0, stream>>>(x, xp, W1_0, W1_1, b1, h, N);

    bn_stats_k<<<512, 128, 0, stream>>>(h, stats, N);
    bn_finalize_k<<<1, 128, 0, stream>>>(stats, gamma, beta, stats + 256 - 256 + 0, 1.f / (float)N);
    // note: bn_finalize writes scale/shift back into stats[0..255] — but it reads
    // stats[0..255] first within the same thread, so do it into a separate buffer:
    // (handled below — see bnp)
    // -- the launch above is replaced by the corrected one using bnp:
    // (kept single definition; see below)

    // Apply BN + ReLU in place on h, then propagate and head GEMMs
    bn_apply_relu_k<<<(N * 32 + 255) / 256, 256, 0, stream>>>(h, stats, N);

    propagate_k<<<pb, 256, 0, stream>>>(h, hp, row_ptr, col, val, N);

    gemm_dual_k<64><<<gb, 256, 0, stream>>>(h, hp, Wmu_0, Wmu_1, b_mu, out_mu, N);
    gemm_dual_k<64><<<gb, 256, 0, stream>>>(h, hp, Wls_0, Wls_1, b_ls, out_ls, N);
}

// Round 2
// 479.042 us; speedup vs baseline: 1.4672x; 1.4672x over previous
//
#include <hip/hip_runtime.h>
#include <cstddef>
#include <cstdint>

static constexpr int IN_C  = 128;
static constexpr int HID_C = 128;
static constexpr int OUT_C = 64;
static constexpr float BN_EPS = 1e-5f;

using bf16x8 = __attribute__((ext_vector_type(8))) short;
using f32x4  = __attribute__((ext_vector_type(4))) float;

__device__ __forceinline__ ushort f2bf(float f) {
    uint u = __float_as_uint(f);
    u += 0x7fffu + ((u >> 16) & 1u);   // round-to-nearest-even
    return (ushort)(u >> 16);
}
__device__ __forceinline__ float bf_lo(uint v) { return __uint_as_float(v << 16); }
__device__ __forceinline__ float bf_hi(uint v) { return __uint_as_float(v & 0xffff0000u); }

// ---------------------------------------------------------------------------
__global__ void edge_deg_k(const int* __restrict__ src, const int* __restrict__ dst,
                           int* __restrict__ deg_src, int* __restrict__ cnt_dst, int e_cnt) {
    int e = blockIdx.x * blockDim.x + threadIdx.x;
    if (e < e_cnt) {
        atomicAdd(&deg_src[src[e]], 1);
        atomicAdd(&cnt_dst[dst[e]], 1);
    }
}

__global__ void dinv_k(const int* __restrict__ deg, float* __restrict__ dinv, int n) {
    int i = blockIdx.x * blockDim.x + threadIdx.x;
    if (i < n) {
        int d = deg[i];
        dinv[i] = (d > 0) ? rsqrtf((float)d) : 0.f;
    }
}

// Shuffle-based exclusive scan: 1024 threads, 4 elems/thread, ~13 outer iters.
__global__ void scan_k(const int* __restrict__ cnt, int* __restrict__ row_ptr, int n) {
    __shared__ int sm_w[16];
    __shared__ int sm_excl[16];
    __shared__ int sm_total;
    int tid = threadIdx.x;
    int lane = tid & 63, wid = tid >> 6;
    int running = 0;
    if (tid == 0) row_ptr[0] = 0;
    for (int base = 0; base < n; base += 4096) {
        int i0 = base + tid * 4;
        int c0 = (i0     < n) ? cnt[i0]     : 0;
        int c1 = (i0 + 1 < n) ? cnt[i0 + 1] : 0;
        int c2 = (i0 + 2 < n) ? cnt[i0 + 2] : 0;
        int c3 = (i0 + 3 < n) ? cnt[i0 + 3] : 0;
        int tsum = c0 + c1 + c2 + c3;
        int s = tsum;
        #pragma unroll
        for (int off = 1; off < 64; off <<= 1) {
            int t = __shfl_up(s, off, 64);
            if (lane >= off) s += t;
        }
        if (lane == 63) sm_w[wid] = s;
        __syncthreads();
        if (tid == 0) {
            int acc = 0;
            #pragma unroll
            for (int w = 0; w < 16; ++w) { sm_excl[w] = acc; acc += sm_w[w]; }
            sm_total = acc;
        }
        __syncthreads();
        int excl = running + sm_excl[wid] + (s - tsum);
        if (i0     < n) row_ptr[i0 + 1] = excl + c0;
        if (i0 + 1 < n) row_ptr[i0 + 2] = excl + c0 + c1;
        if (i0 + 2 < n) row_ptr[i0 + 3] = excl + c0 + c1 + c2;
        if (i0 + 3 < n) row_ptr[i0 + 4] = excl + tsum;
        running += sm_total;
        __syncthreads();
    }
}

__global__ void fill_csr_k(const int* __restrict__ src, const int* __restrict__ dst,
                           const float* __restrict__ dinv, const int* __restrict__ row_ptr,
                           int* __restrict__ cursor, int* __restrict__ col,
                           float* __restrict__ val, int e_cnt) {
    int e = blockIdx.x * blockDim.x + threadIdx.x;
    if (e < e_cnt) {
        int s = src[e], t = dst[e];
        float nv = -dinv[s] * dinv[t];
        int pos = row_ptr[t] + atomicAdd(&cursor[t], 1);
        col[pos] = s;
        val[pos] = nv;
    }
}

// fp32 -> bf16 (pairs packed into uint)
__global__ void convert_x_k(const float* __restrict__ in, ushort* __restrict__ out, int n64) {
    int i = blockIdx.x * blockDim.x + threadIdx.x;
    if (i >= n64) return;
    float2 v = ((const float2*)in)[i];
    ((uint*)out)[i] = (uint)f2bf(v.x) | ((uint)f2bf(v.y) << 16);
}

// Build transposed bf16 weights:
//  Wt1[c][k], c<128, k<256 : [W1_0;W1_1]^T ; bias1 = b1
//  Wt2[c][k], c<128        : cols 0-63 = mu head, 64-127 = logstd head; bias2 = b_mu||b_ls
__global__ void prep_weights_k(const float* __restrict__ W1_0, const float* __restrict__ W1_1,
                               const float* __restrict__ b1,
                               const float* __restrict__ Wmu_0, const float* __restrict__ Wmu_1,
                               const float* __restrict__ b_mu,
                               const float* __restrict__ Wls_0, const float* __restrict__ Wls_1,
                               const float* __restrict__ b_ls,
                               ushort* __restrict__ Wt1, ushort* __restrict__ Wt2,
                               float* __restrict__ bias1, float* __restrict__ bias2) {
    int idx = blockIdx.x * blockDim.x + threadIdx.x;  // 65536
    int which = idx >> 15;
    int c = (idx >> 8) & 127;
    int k = idx & 255;
    if (which == 0) {
        float v = (k < 128) ? W1_0[k * 128 + c] : W1_1[(k - 128) * 128 + c];
        Wt1[c * 256 + k] = f2bf(v);
        if (k == 0) bias1[c] = b1[c];
    } else {
        float v;
        if (c < 64) v = (k < 128) ? Wmu_0[k * 64 + c] : Wmu_1[(k - 128) * 64 + c];
        else        v = (k < 128) ? Wls_0[k * 64 + (c - 64)] : Wls_1[(k - 128) * 64 + (c - 64)];
        Wt2[c * 256 + k] = f2bf(v);
        if (k == 0) bias2[c] = (c < 64) ? b_mu[c] : b_ls[c - 64];
    }
}

// Propagate (bf16 in/out, fp32 accum): one wave per node, lane owns cols {2L,2L+1}
__global__ __launch_bounds__(256) void propagate_bf_k(
    const ushort* __restrict__ in, ushort* __restrict__ out,
    const int* __restrict__ row_ptr, const int* __restrict__ col,
    const float* __restrict__ val, int n) {
    int wid = (blockIdx.x * 256 + threadIdx.x) >> 6;
    if (wid >= n) return;
    int lane = threadIdx.x & 63;
    int s = row_ptr[wid], e = row_ptr[wid + 1];
    float a0 = 0.f, a1 = 0.f;
    for (int i = s; i < e; ++i) {
        int c = col[i];
        float w = val[i];
        uint v = ((const uint*)in)[(size_t)c * 64 + lane];
        a0 += w * bf_lo(v);
        a1 += w * bf_hi(v);
    }
    ((uint*)out)[(size_t)wid * 64 + lane] = (uint)f2bf(a0) | ((uint)f2bf(a1) << 16);
}

// MFMA dual GEMM: C[n,128] = [A0|A1] (bf16, K=256 concat) @ Wt^T + bias
// MODE 0: store bf16 to Cb[n][128].  MODE 1: split fp32 stores (cols<64 -> Cmu, else Cls).
template <int MODE>
__global__ __launch_bounds__(256) void gemm_mfma_k(
    const ushort* __restrict__ A0, const ushort* __restrict__ A1,
    const ushort* __restrict__ Wt, const float* __restrict__ bias,
    ushort* __restrict__ Cb, float* __restrict__ Cmu, float* __restrict__ Cls, int n) {
    __shared__ ushort sA[64][32];    // 64 rows x 32 k
    __shared__ ushort sW[128][32];   // 128 cols x 32 k

    int tid = threadIdx.x;
    int block_row = blockIdx.x * 64;
    int wave = tid >> 6, lane = tid & 63;
    int m_local = wave * 16 + (lane & 15);
    int quad = lane >> 4;

    f32x4 acc[8];
    #pragma unroll
    for (int t = 0; t < 8; ++t) acc[t] = (f32x4){0.f, 0.f, 0.f, 0.f};

    for (int k0 = 0; k0 < 256; k0 += 32) {
        {   // stage A: thread loads 8 bf16 (16B)
            int row = tid >> 2, koff = (tid & 3) * 8;
            int grow = block_row + row;
            int kc = k0 + koff;
            uint4 v = make_uint4(0, 0, 0, 0);
            if (grow < n) {
                const ushort* srcp = (kc < 128) ? (A0 + (size_t)grow * 128 + kc)
                                                : (A1 + (size_t)grow * 128 + (kc - 128));
                v = *(const uint4*)srcp;
            }
            *(uint4*)&sA[row][koff] = v;
        }
        #pragma unroll
        for (int i = tid; i < 512; i += 256) {   // stage W: 128x32 bf16
            int c = i >> 2, koff = (i & 3) * 8;
            *(uint4*)&sW[c][koff] = *(const uint4*)(Wt + (size_t)c * 256 + k0 + koff);
        }
        __syncthreads();
        bf16x8 af = *(const bf16x8*)&sA[m_local][quad * 8];
        #pragma unroll
        for (int t = 0; t < 8; ++t) {
            bf16x8 bfr = *(const bf16x8*)&sW[t * 16 + (lane & 15)][quad * 8];
            acc[t] = __builtin_amdgcn_mfma_f32_16x16x32_bf16(af, bfr, acc[t], 0, 0, 0);
        }
        __syncthreads();
    }

    int col_base = lane & 15;
    int row_l = wave * 16 + quad * 4;
    #pragma unroll
    for (int t = 0; t < 8; ++t) {
        int col = t * 16 + col_base;
        float b = bias[col];
        #pragma unroll
        for (int r = 0; r < 4; ++r) {
            int grow = block_row + row_l + r;
            if (grow < n) {
                float v = acc[t][r] + b;
                if (MODE == 0) {
                    Cb[(size_t)grow * 128 + col] = f2bf(v);
                } else {
                    if (col < 64) Cmu[(size_t)grow * 64 + col] = v;
                    else          Cls[(size_t)grow * 64 + (col - 64)] = v;
                }
            }
        }
    }
}

// BN column stats over bf16 h: per-block LDS reduce, then atomics.
__global__ __launch_bounds__(256) void bn_stats_k(const ushort* __restrict__ hb,
                                                  float* __restrict__ stats, int n) {
    __shared__ float sm[1024];
    int tid = threadIdx.x;
    int p = tid & 63;      // pair -> cols 2p, 2p+1
    int rw = tid >> 6;
    float s0 = 0.f, q0 = 0.f, s1 = 0.f, q1 = 0.f;
    for (int r = blockIdx.x * 4 + rw; r < n; r += gridDim.x * 4) {
        uint v = ((const uint*)hb)[(size_t)r * 64 + p];
        float f0 = bf_lo(v), f1 = bf_hi(v);
        s0 += f0; q0 += f0 * f0;
        s1 += f1; q1 += f1 * f1;
    }
    sm[tid] = s0; sm[256 + tid] = q0; sm[512 + tid] = s1; sm[768 + tid] = q1;
    __syncthreads();
    if (tid < 64) {
        #pragma unroll
        for (int q = 0; q < 4; ++q) {
            float v = sm[q * 256 + tid] + sm[q * 256 + tid + 64] +
                      sm[q * 256 + tid + 128] + sm[q * 256 + tid + 192];
            int col = 2 * tid + (q >> 1);           // q0,q1 -> col 2p ; q2,q3 -> col 2p+1
            atomicAdd(&stats[col + ((q & 1) ? 128 : 0)], v);
        }
    }
}

__global__ void bn_finalize_k(const float* __restrict__ stats, const float* __restrict__ gamma,
                              const float* __restrict__ beta, float* __restrict__ p, float inv_n) {
    int c = threadIdx.x;  // 128
    float mean = stats[c] * inv_n;
    float var = stats[128 + c] * inv_n - mean * mean;
    float sc = gamma[c] * rsqrtf(var + BN_EPS);
    p[c] = sc;
    p[128 + c] = beta[c] - mean * sc;
}

// In-place BN affine + ReLU on bf16 h
__global__ void bn_apply_relu_bf_k(ushort* __restrict__ hb, const float* __restrict__ p, int n64) {
    int i = blockIdx.x * blockDim.x + threadIdx.x;
    if (i >= n64) return;
    int c2 = (i & 63) * 2;
    uint v = ((uint*)hb)[i];
    float f0 = fmaxf(bf_lo(v) * p[c2]     + p[128 + c2],     0.f);
    float f1 = fmaxf(bf_hi(v) * p[c2 + 1] + p[128 + c2 + 1], 0.f);
    ((uint*)hb)[i] = (uint)f2bf(f0) | ((uint)f2bf(f1) << 16);
}

// ---------------------------------------------------------------------------
extern "C" void kernel_launch(void* const* d_in, const int* in_sizes, int n_in,
                              void* d_out, int out_size, void* d_ws, size_t ws_size,
                              hipStream_t stream) {
    const float* x = (const float*)d_in[0];
    const int* edge_index = (const int*)d_in[1];
    const float* W1_0 = (const float*)d_in[2];
    const float* W1_1 = (const float*)d_in[3];
    const float* b1 = (const float*)d_in[4];
    const float* gamma = (const float*)d_in[5];
    const float* beta = (const float*)d_in[6];
    const float* Wmu_0 = (const float*)d_in[7];
    const float* Wmu_1 = (const float*)d_in[8];
    const float* b_mu = (const float*)d_in[9];
    const float* Wls_0 = (const float*)d_in[10];
    const float* Wls_1 = (const float*)d_in[11];
    const float* b_ls = (const float*)d_in[12];

    const int N = in_sizes[0] / IN_C;   // 50000
    const int E = in_sizes[1] / 2;      // 800000
    const int* src = edge_index;
    const int* dst = edge_index + E;

    char* w = (char*)d_ws;
    auto alloc = [&](size_t bytes) {
        char* p = w;
        w += (bytes + 15) & ~(size_t)15;
        return p;
    };
    // zeroed region first
    int* deg_cnt = (int*)alloc((size_t)N * 4);
    int* cnt_dst = (int*)alloc((size_t)N * 4);
    int* cursor  = (int*)alloc((size_t)N * 4);
    float* stats = (float*)alloc(256 * 4);
    size_t zero_bytes = (size_t)(w - (char*)deg_cnt);
    // non-zeroed
    int* row_ptr = (int*)alloc((size_t)(N + 1) * 4);
    float* dinv  = (float*)alloc((size_t)N * 4);
    int* col     = (int*)alloc((size_t)E * 4);
    float* val   = (float*)alloc((size_t)E * 4);
    float* bnp   = (float*)alloc(256 * 4);
    ushort* x_bf  = (ushort*)alloc((size_t)N * 128 * 2);
    ushort* xp_bf = (ushort*)alloc((size_t)N * 128 * 2);
    ushort* h_bf  = (ushort*)alloc((size_t)N * 128 * 2);
    ushort* hp_bf = (ushort*)alloc((size_t)N * 128 * 2);
    ushort* Wt1   = (ushort*)alloc(128 * 256 * 2);
    ushort* Wt2   = (ushort*)alloc(128 * 256 * 2);
    float* bias1  = (float*)alloc(128 * 4);
    float* bias2  = (float*)alloc(128 * 4);

    float* out_mu = (float*)d_out;
    float* out_ls = out_mu + (size_t)N * OUT_C;

    hipMemsetAsync(deg_cnt, 0, zero_bytes, stream);

    int eb = (E + 255) / 256;
    int nb = (N + 255) / 256;
    edge_deg_k<<<eb, 256, 0, stream>>>(src, dst, deg_cnt, cnt_dst, E);
    dinv_k<<<nb, 256, 0, stream>>>(deg_cnt, dinv, N);
    scan_k<<<1, 1024, 0, stream>>>(cnt_dst, row_ptr, N);
    fill_csr_k<<<eb, 256, 0, stream>>>(src, dst, dinv, row_ptr, cursor, col, val, E);

    convert_x_k<<<(N * 64 + 255) / 256, 256, 0, stream>>>(x, x_bf, N * 64);
    prep_weights_k<<<256, 256, 0, stream>>>(W1_0, W1_1, b1, Wmu_0, Wmu_1, b_mu,
                                            Wls_0, Wls_1, b_ls, Wt1, Wt2, bias1, bias2);

    int pb = (N + 3) / 4;
    propagate_bf_k<<<pb, 256, 0, stream>>>(x_bf, xp_bf, row_ptr, col, val, N);

    int gb = (N + 63) / 64;
    gemm_mfma_k<0><<<gb, 256, 0, stream>>>(x_bf, xp_bf, Wt1, bias1, h_bf, nullptr, nullptr, N);

    bn_stats_k<<<256, 256, 0, stream>>>(h_bf, stats, N);
    bn_finalize_k<<<1, 128, 0, stream>>>(stats, gamma, beta, bnp, 1.f / (float)N);
    bn_apply_relu_bf_k<<<(N * 64 + 255) / 256, 256, 0, stream>>>(h_bf, bnp, N * 64);

    propagate_bf_k<<<pb, 256, 0, stream>>>(h_bf, hp_bf, row_ptr, col, val, N);

    gemm_mfma_k<1><<<gb, 256, 0, stream>>>(h_bf, hp_bf, Wt2, bias2, nullptr, out_mu, out_ls, N);
}

// Round 3
// 371.777 us; speedup vs baseline: 1.8905x; 1.2885x over previous
//
#include <hip/hip_runtime.h>
#include <cstddef>
#include <cstdint>

static constexpr int IN_C  = 128;
static constexpr int HID_C = 128;
static constexpr int OUT_C = 64;
static constexpr float BN_EPS = 1e-5f;

using bf16x8 = __attribute__((ext_vector_type(8))) short;
using f32x4  = __attribute__((ext_vector_type(4))) float;

__device__ __forceinline__ ushort f2bf(float f) {
    uint u = __float_as_uint(f);
    u += 0x7fffu + ((u >> 16) & 1u);   // round-to-nearest-even
    return (ushort)(u >> 16);
}
__device__ __forceinline__ uint pack2(float a, float b) {
    return (uint)f2bf(a) | ((uint)f2bf(b) << 16);
}
__device__ __forceinline__ float bf_lo(uint v) { return __uint_as_float(v << 16); }
__device__ __forceinline__ float bf_hi(uint v) { return __uint_as_float(v & 0xffff0000u); }

// ---------------------------------------------------------------------------
__global__ void edge_deg_k(const int* __restrict__ src, const int* __restrict__ dst,
                           int* __restrict__ deg_src, int* __restrict__ cnt_dst, int e_cnt) {
    int e = blockIdx.x * blockDim.x + threadIdx.x;
    if (e < e_cnt) {
        atomicAdd(&deg_src[src[e]], 1);
        atomicAdd(&cnt_dst[dst[e]], 1);
    }
}

__global__ void dinv_k(const int* __restrict__ deg, float* __restrict__ dinv, int n) {
    int i = blockIdx.x * blockDim.x + threadIdx.x;
    if (i < n) {
        int d = deg[i];
        dinv[i] = (d > 0) ? rsqrtf((float)d) : 0.f;
    }
}

// --------------------------- 3-phase scan ----------------------------------
// phase 1: block b (1024 thr, 4096 elems) -> bsum[b]
__global__ void scan_reduce_k(const int* __restrict__ cnt, int* __restrict__ bsum, int n) {
    __shared__ int sw[16];
    int tid = threadIdx.x;
    int i0 = blockIdx.x * 4096 + tid * 4;
    int t = 0;
    if (i0 + 3 < n) {
        int4 c = *(const int4*)(cnt + i0);
        t = c.x + c.y + c.z + c.w;
    } else {
        #pragma unroll
        for (int j = 0; j < 4; ++j) if (i0 + j < n) t += cnt[i0 + j];
    }
    #pragma unroll
    for (int off = 1; off < 64; off <<= 1) t += __shfl_xor(t, off, 64);
    if ((tid & 63) == 0) sw[tid >> 6] = t;
    __syncthreads();
    if (tid == 0) {
        int a = 0;
        #pragma unroll
        for (int w = 0; w < 16; ++w) a += sw[w];
        bsum[blockIdx.x] = a;
    }
}

// phase 2: single wave exclusive-scans bsum[0..nb), nb <= 64
__global__ void scan_bsum_k(int* __restrict__ bsum, int nb) {
    int lane = threadIdx.x;
    int v = (lane < nb) ? bsum[lane] : 0;
    int s = v;
    #pragma unroll
    for (int off = 1; off < 64; off <<= 1) {
        int t = __shfl_up(s, off, 64);
        if (lane >= off) s += t;
    }
    if (lane < nb) bsum[lane] = s - v;
}

// phase 3: per-block scan with base offset
__global__ void scan_phase3_k(const int* __restrict__ cnt, const int* __restrict__ bsum,
                              int* __restrict__ row_ptr, int n) {
    __shared__ int sm_w[16];
    __shared__ int sm_excl[16];
    int tid = threadIdx.x;
    int lane = tid & 63, wid = tid >> 6;
    int base = blockIdx.x * 4096;
    int running = bsum[blockIdx.x];
    if (blockIdx.x == 0 && tid == 0) row_ptr[0] = 0;
    int i0 = base + tid * 4;
    int c0 = (i0     < n) ? cnt[i0]     : 0;
    int c1 = (i0 + 1 < n) ? cnt[i0 + 1] : 0;
    int c2 = (i0 + 2 < n) ? cnt[i0 + 2] : 0;
    int c3 = (i0 + 3 < n) ? cnt[i0 + 3] : 0;
    int tsum = c0 + c1 + c2 + c3;
    int s = tsum;
    #pragma unroll
    for (int off = 1; off < 64; off <<= 1) {
        int t = __shfl_up(s, off, 64);
        if (lane >= off) s += t;
    }
    if (lane == 63) sm_w[wid] = s;
    __syncthreads();
    if (tid == 0) {
        int acc = 0;
        #pragma unroll
        for (int w = 0; w < 16; ++w) { sm_excl[w] = acc; acc += sm_w[w]; }
    }
    __syncthreads();
    int excl = running + sm_excl[wid] + (s - tsum);
    if (i0     < n) row_ptr[i0 + 1] = excl + c0;
    if (i0 + 1 < n) row_ptr[i0 + 2] = excl + c0 + c1;
    if (i0 + 2 < n) row_ptr[i0 + 3] = excl + c0 + c1 + c2;
    if (i0 + 3 < n) row_ptr[i0 + 4] = excl + tsum;
}

// ---------------------------------------------------------------------------
// CSR fill: col only (norm is factored out)
__global__ void fill_csr_k(const int* __restrict__ src, const int* __restrict__ dst,
                           const int* __restrict__ row_ptr, int* __restrict__ cursor,
                           int* __restrict__ col, int e_cnt) {
    int e = blockIdx.x * blockDim.x + threadIdx.x;
    if (e < e_cnt) {
        int t = dst[e];
        int pos = row_ptr[t] + atomicAdd(&cursor[t], 1);
        col[pos] = src[e];
    }
}

// fp32 -> bf16: x_bf (raw) and xs_bf (scaled by dinv[row])
__global__ void convert_x_k(const float* __restrict__ in, const float* __restrict__ dinv,
                            ushort* __restrict__ xb, ushort* __restrict__ xsb, int n64) {
    int i = blockIdx.x * blockDim.x + threadIdx.x;
    if (i >= n64) return;
    int row = i >> 6;
    float d = dinv[row];
    float2 v = ((const float2*)in)[i];
    ((uint*)xb)[i] = pack2(v.x, v.y);
    ((uint*)xsb)[i] = pack2(v.x * d, v.y * d);
}

// Transposed bf16 weights (see round 2)
__global__ void prep_weights_k(const float* __restrict__ W1_0, const float* __restrict__ W1_1,
                               const float* __restrict__ b1,
                               const float* __restrict__ Wmu_0, const float* __restrict__ Wmu_1,
                               const float* __restrict__ b_mu,
                               const float* __restrict__ Wls_0, const float* __restrict__ Wls_1,
                               const float* __restrict__ b_ls,
                               ushort* __restrict__ Wt1, ushort* __restrict__ Wt2,
                               float* __restrict__ bias1, float* __restrict__ bias2) {
    int idx = blockIdx.x * blockDim.x + threadIdx.x;  // 65536
    int which = idx >> 15;
    int c = (idx >> 8) & 127;
    int k = idx & 255;
    if (which == 0) {
        float v = (k < 128) ? W1_0[k * 128 + c] : W1_1[(k - 128) * 128 + c];
        Wt1[c * 256 + k] = f2bf(v);
        if (k == 0) bias1[c] = b1[c];
    } else {
        float v;
        if (c < 64) v = (k < 128) ? Wmu_0[k * 64 + c] : Wmu_1[(k - 128) * 64 + c];
        else        v = (k < 128) ? Wls_0[k * 64 + (c - 64)] : Wls_1[(k - 128) * 64 + (c - 64)];
        Wt2[c * 256 + k] = f2bf(v);
        if (k == 0) bias2[c] = (c < 64) ? b_mu[c] : b_ls[c - 64];
    }
}

// ---------------------------------------------------------------------------
// Propagate: wave per node, 4 groups x 16 lanes; each group owns every 4th edge;
// lane loads uint4 (8 bf16 cols). out[i] = -dinv[i] * sum_{src} xs[src].
#define ACC8(V)                                         \
    acc[0] += bf_lo((V).x); acc[1] += bf_hi((V).x);     \
    acc[2] += bf_lo((V).y); acc[3] += bf_hi((V).y);     \
    acc[4] += bf_lo((V).z); acc[5] += bf_hi((V).z);     \
    acc[6] += bf_lo((V).w); acc[7] += bf_hi((V).w);

__global__ __launch_bounds__(256) void propagate4_k(
    const uint4* __restrict__ xs, uint4* __restrict__ out,
    const int* __restrict__ row_ptr, const int* __restrict__ col,
    const float* __restrict__ dinv, int n) {
    int wid = (blockIdx.x * 256 + threadIdx.x) >> 6;
    if (wid >= n) return;
    int lane = threadIdx.x & 63;
    int g = lane >> 4, li = lane & 15;
    int s = row_ptr[wid], e = row_ptr[wid + 1];
    float acc[8];
    #pragma unroll
    for (int k = 0; k < 8; ++k) acc[k] = 0.f;
    int i = s + g;
    for (; i + 4 < e; i += 8) {
        int c0 = col[i];
        int c1 = col[i + 4];
        uint4 v0 = xs[(size_t)c0 * 16 + li];
        uint4 v1 = xs[(size_t)c1 * 16 + li];
        ACC8(v0);
        ACC8(v1);
    }
    if (i < e) {
        int c0 = col[i];
        uint4 v0 = xs[(size_t)c0 * 16 + li];
        ACC8(v0);
    }
    #pragma unroll
    for (int k = 0; k < 8; ++k) {
        acc[k] += __shfl_xor(acc[k], 16, 64);
        acc[k] += __shfl_xor(acc[k], 32, 64);
    }
    if (g == 0) {
        float sc = -dinv[wid];
        uint4 o;
        o.x = pack2(acc[0] * sc, acc[1] * sc);
        o.y = pack2(acc[2] * sc, acc[3] * sc);
        o.z = pack2(acc[4] * sc, acc[5] * sc);
        o.w = pack2(acc[6] * sc, acc[7] * sc);
        out[(size_t)wid * 16 + li] = o;
    }
}

// ---------------------------------------------------------------------------
// MFMA dual GEMM (unchanged from round 2)
template <int MODE>
__global__ __launch_bounds__(256) void gemm_mfma_k(
    const ushort* __restrict__ A0, const ushort* __restrict__ A1,
    const ushort* __restrict__ Wt, const float* __restrict__ bias,
    ushort* __restrict__ Cb, float* __restrict__ Cmu, float* __restrict__ Cls, int n) {
    __shared__ ushort sA[64][32];
    __shared__ ushort sW[128][32];

    int tid = threadIdx.x;
    int block_row = blockIdx.x * 64;
    int wave = tid >> 6, lane = tid & 63;
    int m_local = wave * 16 + (lane & 15);
    int quad = lane >> 4;

    f32x4 acc[8];
    #pragma unroll
    for (int t = 0; t < 8; ++t) acc[t] = (f32x4){0.f, 0.f, 0.f, 0.f};

    for (int k0 = 0; k0 < 256; k0 += 32) {
        {
            int row = tid >> 2, koff = (tid & 3) * 8;
            int grow = block_row + row;
            int kc = k0 + koff;
            uint4 v = make_uint4(0, 0, 0, 0);
            if (grow < n) {
                const ushort* srcp = (kc < 128) ? (A0 + (size_t)grow * 128 + kc)
                                                : (A1 + (size_t)grow * 128 + (kc - 128));
                v = *(const uint4*)srcp;
            }
            *(uint4*)&sA[row][koff] = v;
        }
        #pragma unroll
        for (int i = tid; i < 512; i += 256) {
            int c = i >> 2, koff = (i & 3) * 8;
            *(uint4*)&sW[c][koff] = *(const uint4*)(Wt + (size_t)c * 256 + k0 + koff);
        }
        __syncthreads();
        bf16x8 af = *(const bf16x8*)&sA[m_local][quad * 8];
        #pragma unroll
        for (int t = 0; t < 8; ++t) {
            bf16x8 bfr = *(const bf16x8*)&sW[t * 16 + (lane & 15)][quad * 8];
            acc[t] = __builtin_amdgcn_mfma_f32_16x16x32_bf16(af, bfr, acc[t], 0, 0, 0);
        }
        __syncthreads();
    }

    int col_base = lane & 15;
    int row_l = wave * 16 + quad * 4;
    #pragma unroll
    for (int t = 0; t < 8; ++t) {
        int col = t * 16 + col_base;
        float b = bias[col];
        #pragma unroll
        for (int r = 0; r < 4; ++r) {
            int grow = block_row + row_l + r;
            if (grow < n) {
                float v = acc[t][r] + b;
                if (MODE == 0) {
                    Cb[(size_t)grow * 128 + col] = f2bf(v);
                } else {
                    if (col < 64) Cmu[(size_t)grow * 64 + col] = v;
                    else          Cls[(size_t)grow * 64 + (col - 64)] = v;
                }
            }
        }
    }
}

// ---------------------------------------------------------------------------
__global__ __launch_bounds__(256) void bn_stats_k(const ushort* __restrict__ hb,
                                                  float* __restrict__ stats, int n) {
    __shared__ float sm[1024];
    int tid = threadIdx.x;
    int p = tid & 63;
    int rw = tid >> 6;
    float s0 = 0.f, q0 = 0.f, s1 = 0.f, q1 = 0.f;
    for (int r = blockIdx.x * 4 + rw; r < n; r += gridDim.x * 4) {
        uint v = ((const uint*)hb)[(size_t)r * 64 + p];
        float f0 = bf_lo(v), f1 = bf_hi(v);
        s0 += f0; q0 += f0 * f0;
        s1 += f1; q1 += f1 * f1;
    }
    sm[tid] = s0; sm[256 + tid] = q0; sm[512 + tid] = s1; sm[768 + tid] = q1;
    __syncthreads();
    if (tid < 64) {
        #pragma unroll
        for (int q = 0; q < 4; ++q) {
            float v = sm[q * 256 + tid] + sm[q * 256 + tid + 64] +
                      sm[q * 256 + tid + 128] + sm[q * 256 + tid + 192];
            int col = 2 * tid + (q >> 1);
            atomicAdd(&stats[col + ((q & 1) ? 128 : 0)], v);
        }
    }
}

__global__ void bn_finalize_k(const float* __restrict__ stats, const float* __restrict__ gamma,
                              const float* __restrict__ beta, float* __restrict__ p, float inv_n) {
    int c = threadIdx.x;  // 128
    float mean = stats[c] * inv_n;
    float var = stats[128 + c] * inv_n - mean * mean;
    float sc = gamma[c] * rsqrtf(var + BN_EPS);
    p[c] = sc;
    p[128 + c] = beta[c] - mean * sc;
}

// BN affine + ReLU in place on h; also write hs = dinv[row] * h for propagate
__global__ void bn_apply_relu_bf_k(ushort* __restrict__ hb, ushort* __restrict__ hsb,
                                   const float* __restrict__ p, const float* __restrict__ dinv,
                                   int n64) {
    int i = blockIdx.x * blockDim.x + threadIdx.x;
    if (i >= n64) return;
    int c2 = (i & 63) * 2;
    int row = i >> 6;
    uint v = ((uint*)hb)[i];
    float f0 = fmaxf(bf_lo(v) * p[c2]     + p[128 + c2],     0.f);
    float f1 = fmaxf(bf_hi(v) * p[c2 + 1] + p[128 + c2 + 1], 0.f);
    ((uint*)hb)[i] = pack2(f0, f1);
    float d = dinv[row];
    ((uint*)hsb)[i] = pack2(f0 * d, f1 * d);
}

// ---------------------------------------------------------------------------
extern "C" void kernel_launch(void* const* d_in, const int* in_sizes, int n_in,
                              void* d_out, int out_size, void* d_ws, size_t ws_size,
                              hipStream_t stream) {
    const float* x = (const float*)d_in[0];
    const int* edge_index = (const int*)d_in[1];
    const float* W1_0 = (const float*)d_in[2];
    const float* W1_1 = (const float*)d_in[3];
    const float* b1 = (const float*)d_in[4];
    const float* gamma = (const float*)d_in[5];
    const float* beta = (const float*)d_in[6];
    const float* Wmu_0 = (const float*)d_in[7];
    const float* Wmu_1 = (const float*)d_in[8];
    const float* b_mu = (const float*)d_in[9];
    const float* Wls_0 = (const float*)d_in[10];
    const float* Wls_1 = (const float*)d_in[11];
    const float* b_ls = (const float*)d_in[12];

    const int N = in_sizes[0] / IN_C;   // 50000
    const int E = in_sizes[1] / 2;      // 800000
    const int* src = edge_index;
    const int* dst = edge_index + E;

    char* w = (char*)d_ws;
    auto alloc = [&](size_t bytes) {
        char* p = w;
        w += (bytes + 15) & ~(size_t)15;
        return p;
    };
    // zeroed region first
    int* deg_cnt = (int*)alloc((size_t)N * 4);
    int* cnt_dst = (int*)alloc((size_t)N * 4);
    int* cursor  = (int*)alloc((size_t)N * 4);
    float* stats = (float*)alloc(256 * 4);
    size_t zero_bytes = (size_t)(w - (char*)deg_cnt);
    // non-zeroed
    int* row_ptr = (int*)alloc((size_t)(N + 1) * 4);
    int* bsum    = (int*)alloc(64 * 4);
    float* dinv  = (float*)alloc((size_t)N * 4);
    int* col     = (int*)alloc((size_t)E * 4);
    float* bnp   = (float*)alloc(256 * 4);
    ushort* x_bf  = (ushort*)alloc((size_t)N * 128 * 2);
    ushort* xs_bf = (ushort*)alloc((size_t)N * 128 * 2);
    ushort* xp_bf = (ushort*)alloc((size_t)N * 128 * 2);
    ushort* h_bf  = (ushort*)alloc((size_t)N * 128 * 2);
    ushort* hs_bf = (ushort*)alloc((size_t)N * 128 * 2);
    ushort* hp_bf = (ushort*)alloc((size_t)N * 128 * 2);
    ushort* Wt1   = (ushort*)alloc(128 * 256 * 2);
    ushort* Wt2   = (ushort*)alloc(128 * 256 * 2);
    float* bias1  = (float*)alloc(128 * 4);
    float* bias2  = (float*)alloc(128 * 4);

    float* out_mu = (float*)d_out;
    float* out_ls = out_mu + (size_t)N * OUT_C;

    hipMemsetAsync(deg_cnt, 0, zero_bytes, stream);

    int eb = (E + 255) / 256;
    int nb256 = (N + 255) / 256;
    int NB = (N + 4095) / 4096;  // 13 scan blocks

    edge_deg_k<<<eb, 256, 0, stream>>>(src, dst, deg_cnt, cnt_dst, E);
    dinv_k<<<nb256, 256, 0, stream>>>(deg_cnt, dinv, N);

    scan_reduce_k<<<NB, 1024, 0, stream>>>(cnt_dst, bsum, N);
    scan_bsum_k<<<1, 64, 0, stream>>>(bsum, NB);
    scan_phase3_k<<<NB, 1024, 0, stream>>>(cnt_dst, bsum, row_ptr, N);

    fill_csr_k<<<eb, 256, 0, stream>>>(src, dst, row_ptr, cursor, col, E);

    convert_x_k<<<(N * 64 + 255) / 256, 256, 0, stream>>>(x, dinv, x_bf, xs_bf, N * 64);
    prep_weights_k<<<256, 256, 0, stream>>>(W1_0, W1_1, b1, Wmu_0, Wmu_1, b_mu,
                                            Wls_0, Wls_1, b_ls, Wt1, Wt2, bias1, bias2);

    int pb = (N + 3) / 4;
    propagate4_k<<<pb, 256, 0, stream>>>((const uint4*)xs_bf, (uint4*)xp_bf,
                                         row_ptr, col, dinv, N);

    int gb = (N + 63) / 64;
    gemm_mfma_k<0><<<gb, 256, 0, stream>>>(x_bf, xp_bf, Wt1, bias1, h_bf, nullptr, nullptr, N);

    bn_stats_k<<<256, 256, 0, stream>>>(h_bf, stats, N);
    bn_finalize_k<<<1, 128, 0, stream>>>(stats, gamma, beta, bnp, 1.f / (float)N);
    bn_apply_relu_bf_k<<<(N * 64 + 255) / 256, 256, 0, stream>>>(h_bf, hs_bf, bnp, dinv, N * 64);

    propagate4_k<<<pb, 256, 0, stream>>>((const uint4*)hs_bf, (uint4*)hp_bf,
                                         row_ptr, col, dinv, N);

    gemm_mfma_k<1><<<gb, 256, 0, stream>>>(h_bf, hp_bf, Wt2, bias2, nullptr, out_mu, out_ls, N);
}

// Round 4
// 310.241 us; speedup vs baseline: 2.2655x; 1.1983x over previous
//
#include <hip/hip_runtime.h>
#include <cstddef>
#include <cstdint>

static constexpr int IN_C  = 128;
static constexpr float BN_EPS = 1e-5f;
static constexpr int OUT_C = 64;

// counting-sort geometry (N=50000, E=800000)
static constexpr int CS_C = 32;      // edge chunks
static constexpr int CS_R = 8;       // node ranges
static constexpr int CS_RANGE = 6250; // max nodes per range

using bf16x8 = __attribute__((ext_vector_type(8))) short;
using f32x4  = __attribute__((ext_vector_type(4))) float;

__device__ __forceinline__ ushort f2bf(float f) {
    uint u = __float_as_uint(f);
    u += 0x7fffu + ((u >> 16) & 1u);
    return (ushort)(u >> 16);
}
__device__ __forceinline__ uint pack2(float a, float b) {
    return (uint)f2bf(a) | ((uint)f2bf(b) << 16);
}
__device__ __forceinline__ float bf_lo(uint v) { return __uint_as_float(v << 16); }
__device__ __forceinline__ float bf_hi(uint v) { return __uint_as_float(v & 0xffff0000u); }

// ---------------------------------------------------------------------------
// K1: per-(range,chunk) LDS histograms of src and dst; plain coalesced flush.
__global__ __launch_bounds__(1024) void hist_k(
    const int* __restrict__ src, const int* __restrict__ dst,
    int* __restrict__ hsrc_part, int* __restrict__ hdst_part,
    int N, int E, int chunk, int range) {
    __shared__ int hs_[CS_RANGE];
    __shared__ int hd_[CS_RANGE];
    int c = blockIdx.x & (CS_C - 1);
    int r = blockIdx.x / CS_C;
    int base = r * range;
    int hi = min(base + range, N);
    int rsz = hi - base;
    for (int j = threadIdx.x; j < rsz; j += 1024) { hs_[j] = 0; hd_[j] = 0; }
    __syncthreads();
    int e0 = c * chunk, e1 = min(e0 + chunk, E);
    for (int i = e0 + threadIdx.x; i < e1; i += 1024) {
        int s = src[i];
        if (s >= base && s < hi) atomicAdd(&hs_[s - base], 1);
        int t = dst[i];
        if (t >= base && t < hi) atomicAdd(&hd_[t - base], 1);
    }
    __syncthreads();
    for (int j = threadIdx.x; j < rsz; j += 1024) {
        hsrc_part[(size_t)c * N + base + j] = hs_[j];
        hdst_part[(size_t)c * N + base + j] = hd_[j];
    }
}

// K2a: reduce partials over chunks -> dinv (fused) and cnt_dst
__global__ void reduce_hist_k(const int* __restrict__ hsrc_part,
                              const int* __restrict__ hdst_part,
                              float* __restrict__ dinv, int* __restrict__ cnt_dst, int N) {
    int v = blockIdx.x * 256 + threadIdx.x;
    if (v >= N) return;
    int a = 0, b = 0;
    for (int c = 0; c < CS_C; ++c) {
        a += hsrc_part[(size_t)c * N + v];
        b += hdst_part[(size_t)c * N + v];
    }
    dinv[v] = (a > 0) ? rsqrtf((float)a) : 0.f;
    cnt_dst[v] = b;
}

// --------------------------- 3-phase scan ----------------------------------
__global__ void scan_reduce_k(const int* __restrict__ cnt, int* __restrict__ bsum, int n) {
    __shared__ int sw[16];
    int tid = threadIdx.x;
    int i0 = blockIdx.x * 4096 + tid * 4;
    int t = 0;
    if (i0 + 3 < n) {
        int4 c = *(const int4*)(cnt + i0);
        t = c.x + c.y + c.z + c.w;
    } else {
        #pragma unroll
        for (int j = 0; j < 4; ++j) if (i0 + j < n) t += cnt[i0 + j];
    }
    #pragma unroll
    for (int off = 1; off < 64; off <<= 1) t += __shfl_xor(t, off, 64);
    if ((tid & 63) == 0) sw[tid >> 6] = t;
    __syncthreads();
    if (tid == 0) {
        int a = 0;
        #pragma unroll
        for (int w = 0; w < 16; ++w) a += sw[w];
        bsum[blockIdx.x] = a;
    }
}

__global__ void scan_bsum_k(int* __restrict__ bsum, int nb) {
    int lane = threadIdx.x;
    int v = (lane < nb) ? bsum[lane] : 0;
    int s = v;
    #pragma unroll
    for (int off = 1; off < 64; off <<= 1) {
        int t = __shfl_up(s, off, 64);
        if (lane >= off) s += t;
    }
    if (lane < nb) bsum[lane] = s - v;
}

__global__ void scan_phase3_k(const int* __restrict__ cnt, const int* __restrict__ bsum,
                              int* __restrict__ row_ptr, int n) {
    __shared__ int sm_w[16];
    __shared__ int sm_excl[16];
    int tid = threadIdx.x;
    int lane = tid & 63, wid = tid >> 6;
    int base = blockIdx.x * 4096;
    int running = bsum[blockIdx.x];
    if (blockIdx.x == 0 && tid == 0) row_ptr[0] = 0;
    int i0 = base + tid * 4;
    int c0 = (i0     < n) ? cnt[i0]     : 0;
    int c1 = (i0 + 1 < n) ? cnt[i0 + 1] : 0;
    int c2 = (i0 + 2 < n) ? cnt[i0 + 2] : 0;
    int c3 = (i0 + 3 < n) ? cnt[i0 + 3] : 0;
    int tsum = c0 + c1 + c2 + c3;
    int s = tsum;
    #pragma unroll
    for (int off = 1; off < 64; off <<= 1) {
        int t = __shfl_up(s, off, 64);
        if (lane >= off) s += t;
    }
    if (lane == 63) sm_w[wid] = s;
    __syncthreads();
    if (tid == 0) {
        int acc = 0;
        #pragma unroll
        for (int w = 0; w < 16; ++w) { sm_excl[w] = acc; acc += sm_w[w]; }
    }
    __syncthreads();
    int excl = running + sm_excl[wid] + (s - tsum);
    if (i0     < n) row_ptr[i0 + 1] = excl + c0;
    if (i0 + 1 < n) row_ptr[i0 + 2] = excl + c0 + c1;
    if (i0 + 2 < n) row_ptr[i0 + 3] = excl + c0 + c1 + c2;
    if (i0 + 3 < n) row_ptr[i0 + 4] = excl + tsum;
}

// K2c: per-node exclusive scan over chunks (in place): part[c][v] -> scatter base
__global__ void chunk_off_k(int* __restrict__ hdst_part, const int* __restrict__ row_ptr, int N) {
    int v = blockIdx.x * 256 + threadIdx.x;
    if (v >= N) return;
    int run = row_ptr[v];
    for (int c = 0; c < CS_C; ++c) {
        size_t idx = (size_t)c * N + v;
        int t = hdst_part[idx];
        hdst_part[idx] = run;
        run += t;
    }
}

// K3: scatter via LDS cursors — no global atomics.
__global__ __launch_bounds__(1024) void scatter_k(
    const int* __restrict__ src, const int* __restrict__ dst,
    const int* __restrict__ off, int* __restrict__ col,
    int N, int E, int chunk, int range) {
    __shared__ int cur[CS_RANGE];
    int c = blockIdx.x & (CS_C - 1);
    int r = blockIdx.x / CS_C;
    int base = r * range;
    int hi = min(base + range, N);
    int rsz = hi - base;
    for (int j = threadIdx.x; j < rsz; j += 1024)
        cur[j] = off[(size_t)c * N + base + j];
    __syncthreads();
    int e0 = c * chunk, e1 = min(e0 + chunk, E);
    for (int i = e0 + threadIdx.x; i < e1; i += 1024) {
        int t = dst[i];
        if (t >= base && t < hi) {
            int pos = atomicAdd(&cur[t - base], 1);
            col[pos] = src[i];
        }
    }
}

// ---------------------------------------------------------------------------
__global__ void convert_x_k(const float* __restrict__ in, const float* __restrict__ dinv,
                            ushort* __restrict__ xb, ushort* __restrict__ xsb, int n64) {
    int i = blockIdx.x * blockDim.x + threadIdx.x;
    if (i >= n64) return;
    int row = i >> 6;
    float d = dinv[row];
    float2 v = ((const float2*)in)[i];
    ((uint*)xb)[i] = pack2(v.x, v.y);
    ((uint*)xsb)[i] = pack2(v.x * d, v.y * d);
}

__global__ void prep_weights_k(const float* __restrict__ W1_0, const float* __restrict__ W1_1,
                               const float* __restrict__ b1,
                               const float* __restrict__ Wmu_0, const float* __restrict__ Wmu_1,
                               const float* __restrict__ b_mu,
                               const float* __restrict__ Wls_0, const float* __restrict__ Wls_1,
                               const float* __restrict__ b_ls,
                               ushort* __restrict__ Wt1, ushort* __restrict__ Wt2,
                               float* __restrict__ bias1, float* __restrict__ bias2) {
    int idx = blockIdx.x * blockDim.x + threadIdx.x;  // 65536
    int which = idx >> 15;
    int c = (idx >> 8) & 127;
    int k = idx & 255;
    if (which == 0) {
        float v = (k < 128) ? W1_0[k * 128 + c] : W1_1[(k - 128) * 128 + c];
        Wt1[c * 256 + k] = f2bf(v);
        if (k == 0) bias1[c] = b1[c];
    } else {
        float v;
        if (c < 64) v = (k < 128) ? Wmu_0[k * 64 + c] : Wmu_1[(k - 128) * 64 + c];
        else        v = (k < 128) ? Wls_0[k * 64 + (c - 64)] : Wls_1[(k - 128) * 64 + (c - 64)];
        Wt2[c * 256 + k] = f2bf(v);
        if (k == 0) bias2[c] = (c < 64) ? b_mu[c] : b_ls[c - 64];
    }
}

// ---------------------------------------------------------------------------
// Propagate: wave per node, 4 groups x 16 lanes, unroll 4 (stride 4 per group).
#define ACC8(V)                                         \
    acc[0] += bf_lo((V).x); acc[1] += bf_hi((V).x);     \
    acc[2] += bf_lo((V).y); acc[3] += bf_hi((V).y);     \
    acc[4] += bf_lo((V).z); acc[5] += bf_hi((V).z);     \
    acc[6] += bf_lo((V).w); acc[7] += bf_hi((V).w);

__global__ __launch_bounds__(256) void propagate4_k(
    const uint4* __restrict__ xs, uint4* __restrict__ out,
    const int* __restrict__ row_ptr, const int* __restrict__ col,
    const float* __restrict__ dinv, int n) {
    int wid = (blockIdx.x * 256 + threadIdx.x) >> 6;
    if (wid >= n) return;
    int lane = threadIdx.x & 63;
    int g = lane >> 4, li = lane & 15;
    int s = row_ptr[wid], e = row_ptr[wid + 1];
    float acc[8];
    #pragma unroll
    for (int k = 0; k < 8; ++k) acc[k] = 0.f;
    int i = s + g;
    for (; i + 12 < e; i += 16) {
        int c0 = col[i];
        int c1 = col[i + 4];
        int c2 = col[i + 8];
        int c3 = col[i + 12];
        uint4 v0 = xs[(size_t)c0 * 16 + li];
        uint4 v1 = xs[(size_t)c1 * 16 + li];
        uint4 v2 = xs[(size_t)c2 * 16 + li];
        uint4 v3 = xs[(size_t)c3 * 16 + li];
        ACC8(v0); ACC8(v1); ACC8(v2); ACC8(v3);
    }
    for (; i < e; i += 4) {
        int c0 = col[i];
        uint4 v0 = xs[(size_t)c0 * 16 + li];
        ACC8(v0);
    }
    #pragma unroll
    for (int k = 0; k < 8; ++k) {
        acc[k] += __shfl_xor(acc[k], 16, 64);
        acc[k] += __shfl_xor(acc[k], 32, 64);
    }
    if (g == 0) {
        float sc = -dinv[wid];
        uint4 o;
        o.x = pack2(acc[0] * sc, acc[1] * sc);
        o.y = pack2(acc[2] * sc, acc[3] * sc);
        o.z = pack2(acc[4] * sc, acc[5] * sc);
        o.w = pack2(acc[6] * sc, acc[7] * sc);
        out[(size_t)wid * 16 + li] = o;
    }
}

// ---------------------------------------------------------------------------
// MFMA dual GEMM (unchanged)
template <int MODE>
__global__ __launch_bounds__(256) void gemm_mfma_k(
    const ushort* __restrict__ A0, const ushort* __restrict__ A1,
    const ushort* __restrict__ Wt, const float* __restrict__ bias,
    ushort* __restrict__ Cb, float* __restrict__ Cmu, float* __restrict__ Cls, int n) {
    __shared__ ushort sA[64][32];
    __shared__ ushort sW[128][32];

    int tid = threadIdx.x;
    int block_row = blockIdx.x * 64;
    int wave = tid >> 6, lane = tid & 63;
    int m_local = wave * 16 + (lane & 15);
    int quad = lane >> 4;

    f32x4 acc[8];
    #pragma unroll
    for (int t = 0; t < 8; ++t) acc[t] = (f32x4){0.f, 0.f, 0.f, 0.f};

    for (int k0 = 0; k0 < 256; k0 += 32) {
        {
            int row = tid >> 2, koff = (tid & 3) * 8;
            int grow = block_row + row;
            int kc = k0 + koff;
            uint4 v = make_uint4(0, 0, 0, 0);
            if (grow < n) {
                const ushort* srcp = (kc < 128) ? (A0 + (size_t)grow * 128 + kc)
                                                : (A1 + (size_t)grow * 128 + (kc - 128));
                v = *(const uint4*)srcp;
            }
            *(uint4*)&sA[row][koff] = v;
        }
        #pragma unroll
        for (int i = tid; i < 512; i += 256) {
            int c = i >> 2, koff = (i & 3) * 8;
            *(uint4*)&sW[c][koff] = *(const uint4*)(Wt + (size_t)c * 256 + k0 + koff);
        }
        __syncthreads();
        bf16x8 af = *(const bf16x8*)&sA[m_local][quad * 8];
        #pragma unroll
        for (int t = 0; t < 8; ++t) {
            bf16x8 bfr = *(const bf16x8*)&sW[t * 16 + (lane & 15)][quad * 8];
            acc[t] = __builtin_amdgcn_mfma_f32_16x16x32_bf16(af, bfr, acc[t], 0, 0, 0);
        }
        __syncthreads();
    }

    int col_base = lane & 15;
    int row_l = wave * 16 + quad * 4;
    #pragma unroll
    for (int t = 0; t < 8; ++t) {
        int col = t * 16 + col_base;
        float b = bias[col];
        #pragma unroll
        for (int r = 0; r < 4; ++r) {
            int grow = block_row + row_l + r;
            if (grow < n) {
                float v = acc[t][r] + b;
                if (MODE == 0) {
                    Cb[(size_t)grow * 128 + col] = f2bf(v);
                } else {
                    if (col < 64) Cmu[(size_t)grow * 64 + col] = v;
                    else          Cls[(size_t)grow * 64 + (col - 64)] = v;
                }
            }
        }
    }
}

// ---------------------------------------------------------------------------
__global__ __launch_bounds__(256) void bn_stats_k(const ushort* __restrict__ hb,
                                                  float* __restrict__ stats, int n) {
    __shared__ float sm[1024];
    int tid = threadIdx.x;
    int p = tid & 63;
    int rw = tid >> 6;
    float s0 = 0.f, q0 = 0.f, s1 = 0.f, q1 = 0.f;
    for (int r = blockIdx.x * 4 + rw; r < n; r += gridDim.x * 4) {
        uint v = ((const uint*)hb)[(size_t)r * 64 + p];
        float f0 = bf_lo(v), f1 = bf_hi(v);
        s0 += f0; q0 += f0 * f0;
        s1 += f1; q1 += f1 * f1;
    }
    sm[tid] = s0; sm[256 + tid] = q0; sm[512 + tid] = s1; sm[768 + tid] = q1;
    __syncthreads();
    if (tid < 64) {
        #pragma unroll
        for (int q = 0; q < 4; ++q) {
            float v = sm[q * 256 + tid] + sm[q * 256 + tid + 64] +
                      sm[q * 256 + tid + 128] + sm[q * 256 + tid + 192];
            int col = 2 * tid + (q >> 1);
            atomicAdd(&stats[col + ((q & 1) ? 128 : 0)], v);
        }
    }
}

__global__ void bn_finalize_k(const float* __restrict__ stats, const float* __restrict__ gamma,
                              const float* __restrict__ beta, float* __restrict__ p, float inv_n) {
    int c = threadIdx.x;  // 128
    float mean = stats[c] * inv_n;
    float var = stats[128 + c] * inv_n - mean * mean;
    float sc = gamma[c] * rsqrtf(var + BN_EPS);
    p[c] = sc;
    p[128 + c] = beta[c] - mean * sc;
}

__global__ void bn_apply_relu_bf_k(ushort* __restrict__ hb, ushort* __restrict__ hsb,
                                   const float* __restrict__ p, const float* __restrict__ dinv,
                                   int n64) {
    int i = blockIdx.x * blockDim.x + threadIdx.x;
    if (i >= n64) return;
    int c2 = (i & 63) * 2;
    int row = i >> 6;
    uint v = ((uint*)hb)[i];
    float f0 = fmaxf(bf_lo(v) * p[c2]     + p[128 + c2],     0.f);
    float f1 = fmaxf(bf_hi(v) * p[c2 + 1] + p[128 + c2 + 1], 0.f);
    ((uint*)hb)[i] = pack2(f0, f1);
    float d = dinv[row];
    ((uint*)hsb)[i] = pack2(f0 * d, f1 * d);
}

// ---------------------------------------------------------------------------
extern "C" void kernel_launch(void* const* d_in, const int* in_sizes, int n_in,
                              void* d_out, int out_size, void* d_ws, size_t ws_size,
                              hipStream_t stream) {
    const float* x = (const float*)d_in[0];
    const int* edge_index = (const int*)d_in[1];
    const float* W1_0 = (const float*)d_in[2];
    const float* W1_1 = (const float*)d_in[3];
    const float* b1 = (const float*)d_in[4];
    const float* gamma = (const float*)d_in[5];
    const float* beta = (const float*)d_in[6];
    const float* Wmu_0 = (const float*)d_in[7];
    const float* Wmu_1 = (const float*)d_in[8];
    const float* b_mu = (const float*)d_in[9];
    const float* Wls_0 = (const float*)d_in[10];
    const float* Wls_1 = (const float*)d_in[11];
    const float* b_ls = (const float*)d_in[12];

    const int N = in_sizes[0] / IN_C;   // 50000
    const int E = in_sizes[1] / 2;      // 800000
    const int* src = edge_index;
    const int* dst = edge_index + E;

    char* w = (char*)d_ws;
    auto alloc = [&](size_t bytes) {
        char* p = w;
        w += (bytes + 15) & ~(size_t)15;
        return p;
    };
    // zeroed region first
    float* stats = (float*)alloc(256 * 4);
    size_t zero_bytes = (size_t)(w - (char*)stats);
    // non-zeroed
    int* row_ptr = (int*)alloc((size_t)(N + 1) * 4);
    int* bsum    = (int*)alloc(64 * 4);
    float* dinv  = (float*)alloc((size_t)N * 4);
    int* cnt_dst = (int*)alloc((size_t)N * 4);
    int* col     = (int*)alloc((size_t)E * 4);
    int* hsrc_part = (int*)alloc((size_t)CS_C * N * 4);   // 6.4 MB
    int* hdst_part = (int*)alloc((size_t)CS_C * N * 4);   // 6.4 MB (becomes offsets)
    float* bnp   = (float*)alloc(256 * 4);
    ushort* x_bf  = (ushort*)alloc((size_t)N * 128 * 2);
    ushort* xs_bf = (ushort*)alloc((size_t)N * 128 * 2);  // later reused as hs
    ushort* xp_bf = (ushort*)alloc((size_t)N * 128 * 2);  // later reused as hp
    ushort* h_bf  = (ushort*)alloc((size_t)N * 128 * 2);
    ushort* Wt1   = (ushort*)alloc(128 * 256 * 2);
    ushort* Wt2   = (ushort*)alloc(128 * 256 * 2);
    float* bias1  = (float*)alloc(128 * 4);
    float* bias2  = (float*)alloc(128 * 4);

    ushort* hs_bf = xs_bf;   // alias: xs dead after propagate1
    ushort* hp_bf = xp_bf;   // alias: xp dead after gemm1

    float* out_mu = (float*)d_out;
    float* out_ls = out_mu + (size_t)N * OUT_C;

    hipMemsetAsync(stats, 0, zero_bytes, stream);

    int chunk = (E + CS_C - 1) / CS_C;    // 25000
    int range = (N + CS_R - 1) / CS_R;    // 6250
    int NB = (N + 4095) / 4096;           // 13 scan blocks

    hist_k<<<CS_R * CS_C, 1024, 0, stream>>>(src, dst, hsrc_part, hdst_part, N, E, chunk, range);
    reduce_hist_k<<<(N + 255) / 256, 256, 0, stream>>>(hsrc_part, hdst_part, dinv, cnt_dst, N);

    scan_reduce_k<<<NB, 1024, 0, stream>>>(cnt_dst, bsum, N);
    scan_bsum_k<<<1, 64, 0, stream>>>(bsum, NB);
    scan_phase3_k<<<NB, 1024, 0, stream>>>(cnt_dst, bsum, row_ptr, N);

    chunk_off_k<<<(N + 255) / 256, 256, 0, stream>>>(hdst_part, row_ptr, N);
    scatter_k<<<CS_R * CS_C, 1024, 0, stream>>>(src, dst, hdst_part, col, N, E, chunk, range);

    convert_x_k<<<(N * 64 + 255) / 256, 256, 0, stream>>>(x, dinv, x_bf, xs_bf, N * 64);
    prep_weights_k<<<256, 256, 0, stream>>>(W1_0, W1_1, b1, Wmu_0, Wmu_1, b_mu,
                                            Wls_0, Wls_1, b_ls, Wt1, Wt2, bias1, bias2);

    int pb = (N + 3) / 4;
    propagate4_k<<<pb, 256, 0, stream>>>((const uint4*)xs_bf, (uint4*)xp_bf,
                                         row_ptr, col, dinv, N);

    int gb = (N + 63) / 64;
    gemm_mfma_k<0><<<gb, 256, 0, stream>>>(x_bf, xp_bf, Wt1, bias1, h_bf, nullptr, nullptr, N);

    bn_stats_k<<<256, 256, 0, stream>>>(h_bf, stats, N);
    bn_finalize_k<<<1, 128, 0, stream>>>(stats, gamma, beta, bnp, 1.f / (float)N);
    bn_apply_relu_bf_k<<<(N * 64 + 255) / 256, 256, 0, stream>>>(h_bf, hs_bf, bnp, dinv, N * 64);

    propagate4_k<<<pb, 256, 0, stream>>>((const uint4*)hs_bf, (uint4*)hp_bf,
                                         row_ptr, col, dinv, N);

    gemm_mfma_k<1><<<gb, 256, 0, stream>>>(h_bf, hp_bf, Wt2, bias2, nullptr, out_mu, out_ls, N);
}